// Round 14
// baseline (295.629 us; speedup 1.0000x reference)
//
#include <hip/hip_runtime.h>

#define EPS 1e-8f
#define BETA 0.8f

typedef __attribute__((ext_vector_type(8))) short bf16x8;
typedef __attribute__((ext_vector_type(4))) float f32x4;
typedef __attribute__((ext_vector_type(4))) float float4v;
typedef __attribute__((ext_vector_type(4))) unsigned short ushort4v;

__device__ __forceinline__ unsigned short f2b(float f) {
  unsigned int u = __builtin_bit_cast(unsigned int, f);
  u += 0x7fffu + ((u >> 16) & 1u);
  return (unsigned short)(u >> 16);
}
__device__ __forceinline__ float b2f(unsigned short u) {
  unsigned int x = (unsigned int)u << 16;
  return __builtin_bit_cast(float, x);
}

// ---------------------------------------------------------------------------
// K1 merged: blocks <8192: At(bf16)=A+0.8S + rowsum -> dis
//            blocks >=8192: conversions (xb, W1T, W2T)
// ---------------------------------------------------------------------------
__global__ __launch_bounds__(256) void k_degree_conv(
    const float* __restrict__ A, const float* __restrict__ S,
    unsigned short* __restrict__ At, float* __restrict__ dis,
    const float* __restrict__ x, unsigned short* __restrict__ xb,
    const float* __restrict__ W1, unsigned short* __restrict__ W1T,
    const float* __restrict__ W2, unsigned short* __restrict__ W2T) {
  __shared__ float wsum[4];
  const int tid = threadIdx.x;
  if (blockIdx.x < 8192) {
    const int row = blockIdx.x;
    const size_t base = (size_t)row * 8192;
    float4v a[8], s[8];
#pragma unroll
    for (int i = 0; i < 8; ++i) {
      const int c = i * 1024 + tid * 4;
      a[i] = __builtin_nontemporal_load(
          reinterpret_cast<const float4v*>(A + base + c));
      s[i] = __builtin_nontemporal_load(
          reinterpret_cast<const float4v*>(S + base + c));
    }
    float sum = 0.f;
#pragma unroll
    for (int i = 0; i < 8; ++i) {
      const int c = i * 1024 + tid * 4;
      float v0 = a[i].x + BETA * s[i].x;
      float v1 = a[i].y + BETA * s[i].y;
      float v2 = a[i].z + BETA * s[i].z;
      float v3 = a[i].w + BETA * s[i].w;
      sum += (v0 + v1) + (v2 + v3);
      ushort4v o = {f2b(v0), f2b(v1), f2b(v2), f2b(v3)};
      *reinterpret_cast<ushort4v*>(At + base + c) = o;
    }
#pragma unroll
    for (int off = 32; off > 0; off >>= 1) sum += __shfl_xor(sum, off, 64);
    if ((tid & 63) == 0) wsum[tid >> 6] = sum;
    __syncthreads();
    if (tid == 0) {
      float d = ((wsum[0] + wsum[1]) + (wsum[2] + wsum[3])) + EPS;
      dis[row] = (d > 0.f) ? 1.0f / sqrtf(d) : 0.f;
    }
  } else {
    const int b = blockIdx.x - 8192;
    if (b < 4096) {
      const int idx = b * 256 + tid;
      float4v v = reinterpret_cast<const float4v*>(x)[idx];
      ushort4v o = {f2b(v.x), f2b(v.y), f2b(v.z), f2b(v.w)};
      reinterpret_cast<ushort4v*>(xb)[idx] = o;
    } else if (b < 4608) {
      const int idx = (b - 4096) * 256 + tid;  // W1 [512][256]
      const int r = idx >> 8, c = idx & 255;
      W1T[c * 512 + r] = f2b(W1[idx]);
    } else {
      const int idx = (b - 4608) * 256 + tid;  // W2 [256][128]
      const int r = idx >> 7, c = idx & 127;
      W2T[c * 256 + r] = f2b(W2[idx]);
    }
  }
}

// ---------------------------------------------------------------------------
// (fallback-path helpers)
// ---------------------------------------------------------------------------
__global__ __launch_bounds__(256) void k_conv_all(
    const float* __restrict__ x, unsigned short* __restrict__ xb,
    const float* __restrict__ W1, unsigned short* __restrict__ W1T,
    const float* __restrict__ W2, unsigned short* __restrict__ W2T) {
  const int b = blockIdx.x;
  if (b < 4096) {
    const int idx = b * 256 + threadIdx.x;
    float4v v = reinterpret_cast<const float4v*>(x)[idx];
    ushort4v o = {f2b(v.x), f2b(v.y), f2b(v.z), f2b(v.w)};
    reinterpret_cast<ushort4v*>(xb)[idx] = o;
  } else if (b < 4608) {
    const int idx = (b - 4096) * 256 + threadIdx.x;
    const int r = idx >> 8, c = idx & 255;
    W1T[c * 512 + r] = f2b(W1[idx]);
  } else {
    const int idx = (b - 4608) * 256 + threadIdx.x;
    const int r = idx >> 7, c = idx & 127;
    W2T[c * 256 + r] = f2b(W2[idx]);
  }
}

__global__ __launch_bounds__(256) void k_degree_convert(
    const float* __restrict__ A, const float* __restrict__ S,
    unsigned short* __restrict__ At, float* __restrict__ dis) {
  const int row = blockIdx.x;
  const int tid = threadIdx.x;
  const size_t base = (size_t)row * 8192;
  float4v a[8], s[8];
#pragma unroll
  for (int i = 0; i < 8; ++i) {
    const int c = i * 1024 + tid * 4;
    a[i] = __builtin_nontemporal_load(
        reinterpret_cast<const float4v*>(A + base + c));
    s[i] = __builtin_nontemporal_load(
        reinterpret_cast<const float4v*>(S + base + c));
  }
  float sum = 0.f;
#pragma unroll
  for (int i = 0; i < 8; ++i) {
    const int c = i * 1024 + tid * 4;
    float v0 = a[i].x + BETA * s[i].x;
    float v1 = a[i].y + BETA * s[i].y;
    float v2 = a[i].z + BETA * s[i].z;
    float v3 = a[i].w + BETA * s[i].w;
    sum += (v0 + v1) + (v2 + v3);
    ushort4v o = {f2b(v0), f2b(v1), f2b(v2), f2b(v3)};
    *reinterpret_cast<ushort4v*>(At + base + c) = o;
  }
#pragma unroll
  for (int off = 32; off > 0; off >>= 1) sum += __shfl_xor(sum, off, 64);
  __shared__ float wsum[4];
  if ((tid & 63) == 0) wsum[tid >> 6] = sum;
  __syncthreads();
  if (tid == 0) {
    float d = ((wsum[0] + wsum[1]) + (wsum[2] + wsum[3])) + EPS;
    dis[row] = (d > 0.f) ? 1.0f / sqrtf(d) : 0.f;
  }
}

// ---------------------------------------------------------------------------
// Small GEMM (4 waves, BMx64 tile): full K, 2-deep. (unchanged)
// ---------------------------------------------------------------------------
template <int BM, int BN, int EPI>
__global__ __launch_bounds__(256) void k_gemm_bt(
    const unsigned short* __restrict__ Ag, const unsigned short* __restrict__ BTg,
    int M, int N, int Kstride, int Kchunk,
    const float* __restrict__ dis, const float* __restrict__ bias,
    float* __restrict__ outf, unsigned short* __restrict__ outb) {
  constexpr int WM = BM / 2, WN = BN / 2;
  constexpr int MF = WM / 16, NF = WN / 16;
  constexpr int NLOADS = BM / 32 + BN / 32;
  __shared__ unsigned short Als[2][BM][64];
  __shared__ unsigned short Bls[2][BN][64];
  const int tid = threadIdx.x;
  const int lane = tid & 63;
  const int wm = (tid >> 6) >> 1, wn = (tid >> 6) & 1;
  const int brow = blockIdx.x * BM, bcol = blockIdx.y * BN;
  const int ar = tid >> 3;
  const int ac = (tid & 7) * 8;
  const int l15 = lane & 15, lk = (lane >> 4) * 8;

  f32x4 acc[MF][NF];
#pragma unroll
  for (int i = 0; i < MF; ++i)
#pragma unroll
    for (int j = 0; j < NF; ++j) acc[i][j] = (f32x4){0.f, 0.f, 0.f, 0.f};

  auto stage = [&](int buf, int k0) {
#pragma unroll
    for (int i = 0; i < BM / 32; ++i) {
      const unsigned short* g =
          Ag + (size_t)(brow + i * 32 + ar) * Kstride + k0 + ac;
      __builtin_amdgcn_global_load_lds(
          (const __attribute__((address_space(1))) void*)g,
          (__attribute__((address_space(3))) void*)&Als[buf][i * 32 + ar][ac],
          16, 0, 0);
    }
#pragma unroll
    for (int i = 0; i < BN / 32; ++i) {
      const unsigned short* g =
          BTg + (size_t)(bcol + i * 32 + ar) * Kstride + k0 + ac;
      __builtin_amdgcn_global_load_lds(
          (const __attribute__((address_space(1))) void*)g,
          (__attribute__((address_space(3))) void*)&Bls[buf][i * 32 + ar][ac],
          16, 0, 0);
    }
  };

  const int nsteps = Kchunk / 64;
  stage(0, 0);
  for (int t = 0; t < nsteps; ++t) {
    const int cur = t & 1;
    if (t + 1 < nsteps) {
      stage(cur ^ 1, (t + 1) * 64);
      asm volatile("s_waitcnt vmcnt(%0)" ::"n"(NLOADS));
    } else {
      asm volatile("s_waitcnt vmcnt(0)");
    }
    __builtin_amdgcn_s_barrier();
    asm volatile("" ::: "memory");
#pragma unroll
    for (int kk = 0; kk < 2; ++kk) {
      bf16x8 afr[MF], bfr[NF];
#pragma unroll
      for (int mi = 0; mi < MF; ++mi)
        afr[mi] = *reinterpret_cast<const bf16x8*>(
            &Als[cur][wm * WM + mi * 16 + l15][kk * 32 + lk]);
#pragma unroll
      for (int ni = 0; ni < NF; ++ni)
        bfr[ni] = *reinterpret_cast<const bf16x8*>(
            &Bls[cur][wn * WN + ni * 16 + l15][kk * 32 + lk]);
#pragma unroll
      for (int mi = 0; mi < MF; ++mi)
#pragma unroll
        for (int ni = 0; ni < NF; ++ni)
          acc[mi][ni] = __builtin_amdgcn_mfma_f32_16x16x32_bf16(
              afr[mi], bfr[ni], acc[mi][ni], 0, 0, 0);
    }
    asm volatile("" ::: "memory");
    __builtin_amdgcn_s_barrier();
  }

  const int crow0 = brow + wm * WM, ccol0 = bcol + wn * WN;
#pragma unroll
  for (int mi = 0; mi < MF; ++mi) {
    const int row0 = crow0 + mi * 16 + (lane >> 4) * 4;
    const float d0 = dis[row0], d1 = dis[row0 + 1], d2 = dis[row0 + 2],
                d3 = dis[row0 + 3];
#pragma unroll
    for (int ni = 0; ni < NF; ++ni) {
      const int col = ccol0 + ni * 16 + l15;
      f32x4 a = acc[mi][ni];
      if constexpr (EPI == 0) {
        ushort4v o = {f2b(d0 * a.x), f2b(d1 * a.y), f2b(d2 * a.z),
                      f2b(d3 * a.w)};
        *reinterpret_cast<ushort4v*>(outb + (size_t)col * M + row0) = o;
      } else if constexpr (EPI == 1) {
        const float bb = bias[col];
        float v0 = d0 * a.x + bb; v0 = v0 > 0.f ? v0 : 0.f;
        float v1 = d1 * a.y + bb; v1 = v1 > 0.f ? v1 : 0.f;
        float v2 = d2 * a.z + bb; v2 = v2 > 0.f ? v2 : 0.f;
        float v3 = d3 * a.w + bb; v3 = v3 > 0.f ? v3 : 0.f;
        outb[(size_t)(row0 + 0) * N + col] = f2b(v0);
        outb[(size_t)(row0 + 1) * N + col] = f2b(v1);
        outb[(size_t)(row0 + 2) * N + col] = f2b(v2);
        outb[(size_t)(row0 + 3) * N + col] = f2b(v3);
      } else {
        const float bb = bias[col];
        outf[(size_t)(row0 + 0) * N + col] = d0 * a.x + bb;
        outf[(size_t)(row0 + 1) * N + col] = d1 * a.y + bb;
        outf[(size_t)(row0 + 2) * N + col] = d2 * a.z + bb;
        outf[(size_t)(row0 + 3) * N + col] = d3 * a.w + bb;
      }
    }
  }
}

// ---------------------------------------------------------------------------
// Layer-1 big GEMM + FUSED finalize. 128x128 tile, 2-deep, swizzled, setprio,
// 2 blocks/CU. N=256, ncol=2, SK=4, grid 512. bf16 P partials.
// Last-of-8 blocks per 128-row stripe: h = relu(dis*ΣP+b1) into reused LDS
// (XOR-swizzled), then M2T = (dis ⊙ (h @ W2))^T with W2T read from global.
// Deterministic: reducer reads ALL slabs from memory (winner-independent).
// ---------------------------------------------------------------------------
__global__ __launch_bounds__(512, 4) void k_gemm_l1(
    const unsigned short* __restrict__ Ag,   // [8192][8192] At
    const unsigned short* __restrict__ BTg,  // [256][8192]  M1T
    unsigned short* __restrict__ P,          // [4][8192][256] bf16
    const unsigned short* __restrict__ W2T,  // [128][256]
    const float* __restrict__ dis, const float* __restrict__ b1,
    unsigned short* __restrict__ M2T,        // [128][8192]
    int* __restrict__ cnt) {
  constexpr int Kstride = 8192, N = 256, Kchunk = 2048, gx = 64;
  constexpr int NLOADS = 4;
  __shared__ unsigned short smem[2][2][128][64];  // [op][buf][row][col]
  __shared__ int lastf;

  const int flat = blockIdx.x;  // 512
  const int cpx = 64;
  const int swz = (flat & 7) * cpx + (flat >> 3);
  const int bx = swz % gx;
  const int rem = swz / gx;     // 0..7
  const int by = rem & 1;       // col half
  const int bz = rem >> 1;      // K-split 0..3

  const int tid = threadIdx.x;
  const int lane = tid & 63;
  const int wid = tid >> 6;
  const int wm = wid >> 2, wn = wid & 3;
  const int brow = bx * 128;
  const int bcol = by * 128;
  const int kbase = bz * Kchunk;
  const int ar = tid >> 3;
  const int acs = ((tid & 7) ^ (ar & 7)) * 8;
  const int l15 = lane & 15;
  const int lk = (lane >> 4) * 8;
  const int rk = (l15 & 7) * 8;

  f32x4 acc[4][2];
#pragma unroll
  for (int i = 0; i < 4; ++i)
#pragma unroll
    for (int j = 0; j < 2; ++j) acc[i][j] = (f32x4){0.f, 0.f, 0.f, 0.f};

  auto stage = [&](int buf, int k0) {
#pragma unroll
    for (int i = 0; i < 2; ++i) {
      const unsigned short* g =
          Ag + (size_t)(brow + i * 64 + ar) * Kstride + k0 + acs;
      __builtin_amdgcn_global_load_lds(
          (const __attribute__((address_space(1))) void*)g,
          (__attribute__((address_space(3))) void*)
              &smem[0][buf][i * 64 + ar][(tid & 7) * 8],
          16, 0, 0);
    }
#pragma unroll
    for (int i = 0; i < 2; ++i) {
      const unsigned short* g =
          BTg + (size_t)(bcol + i * 64 + ar) * Kstride + k0 + acs;
      __builtin_amdgcn_global_load_lds(
          (const __attribute__((address_space(1))) void*)g,
          (__attribute__((address_space(3))) void*)
              &smem[1][buf][i * 64 + ar][(tid & 7) * 8],
          16, 0, 0);
    }
  };

  const int nsteps = Kchunk / 64;
  stage(0, kbase);
  for (int t = 0; t < nsteps; ++t) {
    const int cur = t & 1;
    if (t + 1 < nsteps) {
      stage(cur ^ 1, kbase + (t + 1) * 64);
      asm volatile("s_waitcnt vmcnt(%0)" ::"n"(NLOADS));
    } else {
      asm volatile("s_waitcnt vmcnt(0)");
    }
    __builtin_amdgcn_s_barrier();
    asm volatile("" ::: "memory");
#pragma unroll
    for (int kk = 0; kk < 2; ++kk) {
      bf16x8 afr[4], bfr[2];
#pragma unroll
      for (int mi = 0; mi < 4; ++mi)
        afr[mi] = *reinterpret_cast<const bf16x8*>(
            &smem[0][cur][wm * 64 + mi * 16 + l15][(kk * 32 + lk) ^ rk]);
#pragma unroll
      for (int ni = 0; ni < 2; ++ni)
        bfr[ni] = *reinterpret_cast<const bf16x8*>(
            &smem[1][cur][wn * 32 + ni * 16 + l15][(kk * 32 + lk) ^ rk]);
      __builtin_amdgcn_s_setprio(1);
#pragma unroll
      for (int mi = 0; mi < 4; ++mi)
#pragma unroll
        for (int ni = 0; ni < 2; ++ni)
          acc[mi][ni] = __builtin_amdgcn_mfma_f32_16x16x32_bf16(
              afr[mi], bfr[ni], acc[mi][ni], 0, 0, 0);
      __builtin_amdgcn_s_setprio(0);
    }
    asm volatile("" ::: "memory");
    __builtin_amdgcn_s_barrier();
  }

  // ---- write bf16 partial slab ----
  unsigned short* Pz = P + (size_t)bz * 2097152;  // 8192*256
  const int crow0 = brow + wm * 64, ccol0 = bcol + wn * 32;
#pragma unroll
  for (int mi = 0; mi < 4; ++mi) {
    const int row0 = crow0 + mi * 16 + (lane >> 4) * 4;
#pragma unroll
    for (int ni = 0; ni < 2; ++ni) {
      const int col = ccol0 + ni * 16 + l15;
      f32x4 a = acc[mi][ni];
      Pz[(size_t)(row0 + 0) * N + col] = f2b(a.x);
      Pz[(size_t)(row0 + 1) * N + col] = f2b(a.y);
      Pz[(size_t)(row0 + 2) * N + col] = f2b(a.z);
      Pz[(size_t)(row0 + 3) * N + col] = f2b(a.w);
    }
  }

  // ---- arrival ----
  __syncthreads();  // all stores retired (vmcnt0) before fence
  if (tid == 0) {
    __threadfence();                       // XCD L2 writeback (release)
    int r = atomicAdd(&cnt[bx], 1);
    __threadfence();                       // acquire
    lastf = (r == 7) ? 1 : 0;
  }
  __syncthreads();
  if (!lastf) return;

  // ---- finalize: h = relu(dis*ΣP + b1) into reused LDS (swizzled) ----
  unsigned short(*hls)[256] =
      reinterpret_cast<unsigned short(*)[256]>(&smem[0][0][0][0]);
#pragma unroll
  for (int i = 0; i < 16; ++i) {
    const int fi = tid + i * 512;        // 8192 quads
    const int row = fi >> 6;             // 0..127
    const int c4 = (fi & 63) * 4;        // 0..252
    const size_t off = (size_t)(brow + row) * 256 + c4;
    float r0 = 0.f, r1 = 0.f, r2 = 0.f, r3 = 0.f;
#pragma unroll
    for (int z = 0; z < 4; ++z) {
      ushort4v v =
          *reinterpret_cast<const ushort4v*>(P + (size_t)z * 2097152 + off);
      r0 += b2f(v.x); r1 += b2f(v.y); r2 += b2f(v.z); r3 += b2f(v.w);
    }
    const float dm = dis[brow + row];
    const float4v bv = *reinterpret_cast<const float4v*>(b1 + c4);
    r0 = dm * r0 + bv.x; r1 = dm * r1 + bv.y;
    r2 = dm * r2 + bv.z; r3 = dm * r3 + bv.w;
    r0 = r0 > 0.f ? r0 : 0.f;
    r1 = r1 > 0.f ? r1 : 0.f;
    r2 = r2 > 0.f ? r2 : 0.f;
    r3 = r3 > 0.f ? r3 : 0.f;
    const int ch = c4 >> 3, sub = c4 & 7;
    ushort4v o = {f2b(r0), f2b(r1), f2b(r2), f2b(r3)};
    *reinterpret_cast<ushort4v*>(&hls[row][((ch ^ (row & 7)) << 3) + sub]) = o;
  }
  __syncthreads();

  // ---- M2T tile = (dis ⊙ (h @ W2))^T   (output 128 rows x 128 cols) ----
  const int m0w = (wid >> 1) * 32;  // 4 M-groups of 32
  const int n0w = (wid & 1) * 64;   // 2 N-groups of 64
  f32x4 acc2[2][4];
#pragma unroll
  for (int i = 0; i < 2; ++i)
#pragma unroll
    for (int j = 0; j < 4; ++j) acc2[i][j] = (f32x4){0.f, 0.f, 0.f, 0.f};
#pragma unroll
  for (int kk = 0; kk < 8; ++kk) {
    const int gch = kk * 4 + (lane >> 4);  // k-chunk 0..31
    bf16x8 a2[2], b2v[4];
#pragma unroll
    for (int mi = 0; mi < 2; ++mi) {
      const int mr = m0w + mi * 16 + l15;
      a2[mi] = *reinterpret_cast<const bf16x8*>(
          &hls[mr][((gch ^ (mr & 7)) << 3)]);
    }
#pragma unroll
    for (int ni = 0; ni < 4; ++ni) {
      const int nr = n0w + ni * 16 + l15;
      b2v[ni] = *reinterpret_cast<const bf16x8*>(W2T + nr * 256 + gch * 8);
    }
#pragma unroll
    for (int mi = 0; mi < 2; ++mi)
#pragma unroll
      for (int ni = 0; ni < 4; ++ni)
        acc2[mi][ni] = __builtin_amdgcn_mfma_f32_16x16x32_bf16(
            a2[mi], b2v[ni], acc2[mi][ni], 0, 0, 0);
  }
#pragma unroll
  for (int mi = 0; mi < 2; ++mi) {
    const int r0 = m0w + mi * 16 + (lane >> 4) * 4;
    const float d0 = dis[brow + r0], d1 = dis[brow + r0 + 1],
                d2 = dis[brow + r0 + 2], d3 = dis[brow + r0 + 3];
#pragma unroll
    for (int ni = 0; ni < 4; ++ni) {
      const int col = n0w + ni * 16 + l15;
      f32x4 a = acc2[mi][ni];
      ushort4v o = {f2b(d0 * a.x), f2b(d1 * a.y), f2b(d2 * a.z),
                    f2b(d3 * a.w)};
      *reinterpret_cast<ushort4v*>(&M2T[(size_t)col * 8192 + brow + r0]) = o;
    }
  }
}

// ---------------------------------------------------------------------------
// Layer-2 big GEMM + FUSED finalize. 128x128 tile, N=128, ncol=1, SK=8,
// grid 512, 2 blocks/CU. Last-of-8 per stripe: out = dis*ΣP + b2 (f32).
// ---------------------------------------------------------------------------
__global__ __launch_bounds__(512, 4) void k_gemm_l2(
    const unsigned short* __restrict__ Ag,   // [8192][8192] At
    const unsigned short* __restrict__ BTg,  // [128][8192]  M2T
    unsigned short* __restrict__ P,          // [8][8192][128] bf16
    const float* __restrict__ dis, const float* __restrict__ b2,
    float* __restrict__ out,                 // [8192][128] f32
    int* __restrict__ cnt) {
  constexpr int Kstride = 8192, N = 128, Kchunk = 1024, gx = 64;
  constexpr int NLOADS = 4;
  __shared__ unsigned short Als[2][128][64];
  __shared__ unsigned short Bls[2][128][64];
  __shared__ int lastf;

  const int flat = blockIdx.x;  // 512
  const int swz = (flat & 7) * 64 + (flat >> 3);
  const int bx = swz % gx;
  const int bz = swz / gx;      // 0..7

  const int tid = threadIdx.x;
  const int lane = tid & 63;
  const int wid = tid >> 6;
  const int wm = wid >> 2, wn = wid & 3;
  const int brow = bx * 128;
  const int kbase = bz * Kchunk;
  const int ar = tid >> 3;
  const int acs = ((tid & 7) ^ (ar & 7)) * 8;
  const int l15 = lane & 15;
  const int lk = (lane >> 4) * 8;
  const int rk = (l15 & 7) * 8;

  f32x4 acc[4][2];
#pragma unroll
  for (int i = 0; i < 4; ++i)
#pragma unroll
    for (int j = 0; j < 2; ++j) acc[i][j] = (f32x4){0.f, 0.f, 0.f, 0.f};

  auto stage = [&](int buf, int k0) {
#pragma unroll
    for (int i = 0; i < 2; ++i) {
      const unsigned short* g =
          Ag + (size_t)(brow + i * 64 + ar) * Kstride + k0 + acs;
      __builtin_amdgcn_global_load_lds(
          (const __attribute__((address_space(1))) void*)g,
          (__attribute__((address_space(3))) void*)
              &Als[buf][i * 64 + ar][(tid & 7) * 8],
          16, 0, 0);
    }
#pragma unroll
    for (int i = 0; i < 2; ++i) {
      const unsigned short* g =
          BTg + (size_t)(i * 64 + ar) * Kstride + k0 + acs;
      __builtin_amdgcn_global_load_lds(
          (const __attribute__((address_space(1))) void*)g,
          (__attribute__((address_space(3))) void*)
              &Bls[buf][i * 64 + ar][(tid & 7) * 8],
          16, 0, 0);
    }
  };

  const int nsteps = Kchunk / 64;
  stage(0, kbase);
  for (int t = 0; t < nsteps; ++t) {
    const int cur = t & 1;
    if (t + 1 < nsteps) {
      stage(cur ^ 1, kbase + (t + 1) * 64);
      asm volatile("s_waitcnt vmcnt(%0)" ::"n"(NLOADS));
    } else {
      asm volatile("s_waitcnt vmcnt(0)");
    }
    __builtin_amdgcn_s_barrier();
    asm volatile("" ::: "memory");
#pragma unroll
    for (int kk = 0; kk < 2; ++kk) {
      bf16x8 afr[4], bfr[2];
#pragma unroll
      for (int mi = 0; mi < 4; ++mi)
        afr[mi] = *reinterpret_cast<const bf16x8*>(
            &Als[cur][wm * 64 + mi * 16 + l15][(kk * 32 + lk) ^ rk]);
#pragma unroll
      for (int ni = 0; ni < 2; ++ni)
        bfr[ni] = *reinterpret_cast<const bf16x8*>(
            &Bls[cur][wn * 32 + ni * 16 + l15][(kk * 32 + lk) ^ rk]);
      __builtin_amdgcn_s_setprio(1);
#pragma unroll
      for (int mi = 0; mi < 4; ++mi)
#pragma unroll
        for (int ni = 0; ni < 2; ++ni)
          acc[mi][ni] = __builtin_amdgcn_mfma_f32_16x16x32_bf16(
              afr[mi], bfr[ni], acc[mi][ni], 0, 0, 0);
      __builtin_amdgcn_s_setprio(0);
    }
    asm volatile("" ::: "memory");
    __builtin_amdgcn_s_barrier();
  }

  unsigned short* Pz = P + (size_t)bz * 1048576;  // 8192*128
  const int crow0 = brow + wm * 64, ccol0 = wn * 32;
#pragma unroll
  for (int mi = 0; mi < 4; ++mi) {
    const int row0 = crow0 + mi * 16 + (lane >> 4) * 4;
#pragma unroll
    for (int ni = 0; ni < 2; ++ni) {
      const int col = ccol0 + ni * 16 + l15;
      f32x4 a = acc[mi][ni];
      Pz[(size_t)(row0 + 0) * N + col] = f2b(a.x);
      Pz[(size_t)(row0 + 1) * N + col] = f2b(a.y);
      Pz[(size_t)(row0 + 2) * N + col] = f2b(a.z);
      Pz[(size_t)(row0 + 3) * N + col] = f2b(a.w);
    }
  }

  __syncthreads();
  if (tid == 0) {
    __threadfence();
    int r = atomicAdd(&cnt[bx], 1);
    __threadfence();
    lastf = (r == 7) ? 1 : 0;
  }
  __syncthreads();
  if (!lastf) return;

  // finalize: out = dis*Σ + b2
#pragma unroll
  for (int i = 0; i < 8; ++i) {
    const int fi = tid + i * 512;      // 4096 quads
    const int row = fi >> 5;           // 0..127
    const int c4 = (fi & 31) * 4;      // 0..124
    const size_t off = (size_t)(brow + row) * 128 + c4;
    float r0 = 0.f, r1 = 0.f, r2 = 0.f, r3 = 0.f;
#pragma unroll
    for (int z = 0; z < 8; ++z) {
      ushort4v v =
          *reinterpret_cast<const ushort4v*>(P + (size_t)z * 1048576 + off);
      r0 += b2f(v.x); r1 += b2f(v.y); r2 += b2f(v.z); r3 += b2f(v.w);
    }
    const float dm = dis[brow + row];
    const float4v bv = *reinterpret_cast<const float4v*>(b2 + c4);
    float4v o = {dm * r0 + bv.x, dm * r1 + bv.y, dm * r2 + bv.z,
                 dm * r3 + bv.w};
    *reinterpret_cast<float4v*>(out + off) = o;
  }
}

// ---------------------------------------------------------------------------
extern "C" void kernel_launch(void* const* d_in, const int* in_sizes, int n_in,
                              void* d_out, int out_size, void* d_ws,
                              size_t ws_size, hipStream_t stream) {
  const float* A  = (const float*)d_in[0];
  const float* S  = (const float*)d_in[1];
  const float* x  = (const float*)d_in[2];
  const float* W1 = (const float*)d_in[3];
  const float* b1 = (const float*)d_in[4];
  const float* W2 = (const float*)d_in[5];
  const float* b2 = (const float*)d_in[6];
  float* out = (float*)d_out;

  char* ws = (char*)d_ws;
  dim3 blk(256);

  const size_t O_At = 0, O_xb = 134217728, O_M1T = 142606336,
               O_P = 146800640, O_W1T = 180355072, O_W2T = 180617216,
               O_dis = 180682752, O_cnt = 180715520, NEED = 180716544;

  if (ws_size >= NEED) {
    unsigned short* At  = (unsigned short*)(ws + O_At);
    unsigned short* xb  = (unsigned short*)(ws + O_xb);
    unsigned short* M1T = (unsigned short*)(ws + O_M1T);
    unsigned short* P   = (unsigned short*)(ws + O_P);
    unsigned short* M2T = (unsigned short*)(ws + O_xb);   // overlay xb
    unsigned short* W1T = (unsigned short*)(ws + O_W1T);
    unsigned short* W2T = (unsigned short*)(ws + O_W2T);
    float*          dis = (float*)(ws + O_dis);
    int*            cnt = (int*)(ws + O_cnt);

    // 0. zero split-K arrival counters (128 ints)
    hipMemsetAsync(cnt, 0, 512, stream);
    // 1. degree + all conversions (merged)
    k_degree_conv<<<12928, blk, 0, stream>>>(A, S, At, dis, x, xb, W1, W1T,
                                             W2, W2T);
    // 2. M1^T = (dis ⊙ (x @ W1))^T   [256][8192]
    k_gemm_bt<128, 64, 0><<<dim3(64, 4), blk, 0, stream>>>(
        xb, W1T, 8192, 256, 512, 512, dis, nullptr, nullptr, M1T);
    // 3. L1 GEMM + fused h/M2T finalize
    k_gemm_l1<<<dim3(512), dim3(512), 0, stream>>>(At, M1T, P, W2T, dis, b1,
                                                   M2T, cnt);
    // 4. L2 GEMM + fused out finalize
    k_gemm_l2<<<dim3(512), dim3(512), 0, stream>>>(At, M2T, P, dis, b2, out,
                                                   cnt + 64);
  } else {
    unsigned short* At  = (unsigned short*)(ws);
    unsigned short* xb  = (unsigned short*)(ws + 134217728);
    unsigned short* M1T = (unsigned short*)(ws + 142606336);
    unsigned short* hb  = (unsigned short*)(ws + 146800640);
    unsigned short* M2T = (unsigned short*)(ws + 150994944);
    unsigned short* W1T = (unsigned short*)(ws + 153092096);
    unsigned short* W2T = (unsigned short*)(ws + 153354240);
    float* dis          = (float*)(ws + 153419776);

    k_degree_convert<<<8192, blk, 0, stream>>>(A, S, At, dis);
    k_conv_all<<<4736, blk, 0, stream>>>(x, xb, W1, W1T, W2, W2T);
    k_gemm_bt<128, 64, 0><<<dim3(64, 4), blk, 0, stream>>>(
        xb, W1T, 8192, 256, 512, 512, dis, nullptr, nullptr, M1T);
    k_gemm_bt<128, 64, 1><<<dim3(64, 4), blk, 0, stream>>>(
        At, M1T, 8192, 256, 8192, 8192, dis, b1, nullptr, hb);
    k_gemm_bt<64, 64, 0><<<dim3(128, 2), blk, 0, stream>>>(
        hb, W2T, 8192, 128, 256, 256, dis, nullptr, nullptr, M2T);
    k_gemm_bt<64, 64, 2><<<dim3(128, 2), blk, 0, stream>>>(
        At, M2T, 8192, 128, 8192, 8192, dis, b2, out, nullptr);
  }
}

// Round 15
// 196.055 us; speedup vs baseline: 1.5079x; 1.5079x over previous
//
#include <hip/hip_runtime.h>

#define EPS 1e-8f
#define BETA 0.8f

typedef __attribute__((ext_vector_type(8))) short bf16x8;
typedef __attribute__((ext_vector_type(4))) float f32x4;
typedef __attribute__((ext_vector_type(4))) float float4v;
typedef __attribute__((ext_vector_type(4))) unsigned short ushort4v;

__device__ __forceinline__ unsigned short f2b(float f) {
  unsigned int u = __builtin_bit_cast(unsigned int, f);
  u += 0x7fffu + ((u >> 16) & 1u);
  return (unsigned short)(u >> 16);
}
__device__ __forceinline__ float b2f(unsigned short u) {
  unsigned int x = (unsigned int)u << 16;
  return __builtin_bit_cast(float, x);
}

// ---------------------------------------------------------------------------
// K1 merged: blocks <8192: At(bf16)=A+0.8S + rowsum -> dis
//            blocks >=8192: conversions (xb, W1T, W2T)
// ---------------------------------------------------------------------------
__global__ __launch_bounds__(256) void k_degree_conv(
    const float* __restrict__ A, const float* __restrict__ S,
    unsigned short* __restrict__ At, float* __restrict__ dis,
    const float* __restrict__ x, unsigned short* __restrict__ xb,
    const float* __restrict__ W1, unsigned short* __restrict__ W1T,
    const float* __restrict__ W2, unsigned short* __restrict__ W2T) {
  __shared__ float wsum[4];
  const int tid = threadIdx.x;
  if (blockIdx.x < 8192) {
    const int row = blockIdx.x;
    const size_t base = (size_t)row * 8192;
    float4v a[8], s[8];
#pragma unroll
    for (int i = 0; i < 8; ++i) {
      const int c = i * 1024 + tid * 4;
      a[i] = __builtin_nontemporal_load(
          reinterpret_cast<const float4v*>(A + base + c));
      s[i] = __builtin_nontemporal_load(
          reinterpret_cast<const float4v*>(S + base + c));
    }
    float sum = 0.f;
#pragma unroll
    for (int i = 0; i < 8; ++i) {
      const int c = i * 1024 + tid * 4;
      float v0 = a[i].x + BETA * s[i].x;
      float v1 = a[i].y + BETA * s[i].y;
      float v2 = a[i].z + BETA * s[i].z;
      float v3 = a[i].w + BETA * s[i].w;
      sum += (v0 + v1) + (v2 + v3);
      ushort4v o = {f2b(v0), f2b(v1), f2b(v2), f2b(v3)};
      *reinterpret_cast<ushort4v*>(At + base + c) = o;
    }
#pragma unroll
    for (int off = 32; off > 0; off >>= 1) sum += __shfl_xor(sum, off, 64);
    if ((tid & 63) == 0) wsum[tid >> 6] = sum;
    __syncthreads();
    if (tid == 0) {
      float d = ((wsum[0] + wsum[1]) + (wsum[2] + wsum[3])) + EPS;
      dis[row] = (d > 0.f) ? 1.0f / sqrtf(d) : 0.f;
    }
  } else {
    const int b = blockIdx.x - 8192;
    if (b < 4096) {
      const int idx = b * 256 + tid;
      float4v v = reinterpret_cast<const float4v*>(x)[idx];
      ushort4v o = {f2b(v.x), f2b(v.y), f2b(v.z), f2b(v.w)};
      reinterpret_cast<ushort4v*>(xb)[idx] = o;
    } else if (b < 4608) {
      const int idx = (b - 4096) * 256 + tid;  // W1 [512][256]
      const int r = idx >> 8, c = idx & 255;
      W1T[c * 512 + r] = f2b(W1[idx]);
    } else {
      const int idx = (b - 4608) * 256 + tid;  // W2 [256][128]
      const int r = idx >> 7, c = idx & 127;
      W2T[c * 256 + r] = f2b(W2[idx]);
    }
  }
}

// ---------------------------------------------------------------------------
// (fallback-path helpers)
// ---------------------------------------------------------------------------
__global__ __launch_bounds__(256) void k_conv_all(
    const float* __restrict__ x, unsigned short* __restrict__ xb,
    const float* __restrict__ W1, unsigned short* __restrict__ W1T,
    const float* __restrict__ W2, unsigned short* __restrict__ W2T) {
  const int b = blockIdx.x;
  if (b < 4096) {
    const int idx = b * 256 + threadIdx.x;
    float4v v = reinterpret_cast<const float4v*>(x)[idx];
    ushort4v o = {f2b(v.x), f2b(v.y), f2b(v.z), f2b(v.w)};
    reinterpret_cast<ushort4v*>(xb)[idx] = o;
  } else if (b < 4608) {
    const int idx = (b - 4096) * 256 + threadIdx.x;
    const int r = idx >> 8, c = idx & 255;
    W1T[c * 512 + r] = f2b(W1[idx]);
  } else {
    const int idx = (b - 4608) * 256 + threadIdx.x;
    const int r = idx >> 7, c = idx & 127;
    W2T[c * 256 + r] = f2b(W2[idx]);
  }
}

__global__ __launch_bounds__(256) void k_degree_convert(
    const float* __restrict__ A, const float* __restrict__ S,
    unsigned short* __restrict__ At, float* __restrict__ dis) {
  const int row = blockIdx.x;
  const int tid = threadIdx.x;
  const size_t base = (size_t)row * 8192;
  float4v a[8], s[8];
#pragma unroll
  for (int i = 0; i < 8; ++i) {
    const int c = i * 1024 + tid * 4;
    a[i] = __builtin_nontemporal_load(
        reinterpret_cast<const float4v*>(A + base + c));
    s[i] = __builtin_nontemporal_load(
        reinterpret_cast<const float4v*>(S + base + c));
  }
  float sum = 0.f;
#pragma unroll
  for (int i = 0; i < 8; ++i) {
    const int c = i * 1024 + tid * 4;
    float v0 = a[i].x + BETA * s[i].x;
    float v1 = a[i].y + BETA * s[i].y;
    float v2 = a[i].z + BETA * s[i].z;
    float v3 = a[i].w + BETA * s[i].w;
    sum += (v0 + v1) + (v2 + v3);
    ushort4v o = {f2b(v0), f2b(v1), f2b(v2), f2b(v3)};
    *reinterpret_cast<ushort4v*>(At + base + c) = o;
  }
#pragma unroll
  for (int off = 32; off > 0; off >>= 1) sum += __shfl_xor(sum, off, 64);
  __shared__ float wsum[4];
  if ((tid & 63) == 0) wsum[tid >> 6] = sum;
  __syncthreads();
  if (tid == 0) {
    float d = ((wsum[0] + wsum[1]) + (wsum[2] + wsum[3])) + EPS;
    dis[row] = (d > 0.f) ? 1.0f / sqrtf(d) : 0.f;
  }
}

// ---------------------------------------------------------------------------
// Small GEMM (4 waves, BMx64 tile): full K, 2-deep.
// ---------------------------------------------------------------------------
template <int BM, int BN, int EPI>
__global__ __launch_bounds__(256) void k_gemm_bt(
    const unsigned short* __restrict__ Ag, const unsigned short* __restrict__ BTg,
    int M, int N, int Kstride, int Kchunk,
    const float* __restrict__ dis, const float* __restrict__ bias,
    float* __restrict__ outf, unsigned short* __restrict__ outb) {
  constexpr int WM = BM / 2, WN = BN / 2;
  constexpr int MF = WM / 16, NF = WN / 16;
  constexpr int NLOADS = BM / 32 + BN / 32;
  __shared__ unsigned short Als[2][BM][64];
  __shared__ unsigned short Bls[2][BN][64];
  const int tid = threadIdx.x;
  const int lane = tid & 63;
  const int wm = (tid >> 6) >> 1, wn = (tid >> 6) & 1;
  const int brow = blockIdx.x * BM, bcol = blockIdx.y * BN;
  const int ar = tid >> 3;
  const int ac = (tid & 7) * 8;
  const int l15 = lane & 15, lk = (lane >> 4) * 8;

  f32x4 acc[MF][NF];
#pragma unroll
  for (int i = 0; i < MF; ++i)
#pragma unroll
    for (int j = 0; j < NF; ++j) acc[i][j] = (f32x4){0.f, 0.f, 0.f, 0.f};

  auto stage = [&](int buf, int k0) {
#pragma unroll
    for (int i = 0; i < BM / 32; ++i) {
      const unsigned short* g =
          Ag + (size_t)(brow + i * 32 + ar) * Kstride + k0 + ac;
      __builtin_amdgcn_global_load_lds(
          (const __attribute__((address_space(1))) void*)g,
          (__attribute__((address_space(3))) void*)&Als[buf][i * 32 + ar][ac],
          16, 0, 0);
    }
#pragma unroll
    for (int i = 0; i < BN / 32; ++i) {
      const unsigned short* g =
          BTg + (size_t)(bcol + i * 32 + ar) * Kstride + k0 + ac;
      __builtin_amdgcn_global_load_lds(
          (const __attribute__((address_space(1))) void*)g,
          (__attribute__((address_space(3))) void*)&Bls[buf][i * 32 + ar][ac],
          16, 0, 0);
    }
  };

  const int nsteps = Kchunk / 64;
  stage(0, 0);
  for (int t = 0; t < nsteps; ++t) {
    const int cur = t & 1;
    if (t + 1 < nsteps) {
      stage(cur ^ 1, (t + 1) * 64);
      asm volatile("s_waitcnt vmcnt(%0)" ::"n"(NLOADS));
    } else {
      asm volatile("s_waitcnt vmcnt(0)");
    }
    __builtin_amdgcn_s_barrier();
    asm volatile("" ::: "memory");
#pragma unroll
    for (int kk = 0; kk < 2; ++kk) {
      bf16x8 afr[MF], bfr[NF];
#pragma unroll
      for (int mi = 0; mi < MF; ++mi)
        afr[mi] = *reinterpret_cast<const bf16x8*>(
            &Als[cur][wm * WM + mi * 16 + l15][kk * 32 + lk]);
#pragma unroll
      for (int ni = 0; ni < NF; ++ni)
        bfr[ni] = *reinterpret_cast<const bf16x8*>(
            &Bls[cur][wn * WN + ni * 16 + l15][kk * 32 + lk]);
#pragma unroll
      for (int mi = 0; mi < MF; ++mi)
#pragma unroll
        for (int ni = 0; ni < NF; ++ni)
          acc[mi][ni] = __builtin_amdgcn_mfma_f32_16x16x32_bf16(
              afr[mi], bfr[ni], acc[mi][ni], 0, 0, 0);
    }
    asm volatile("" ::: "memory");
    __builtin_amdgcn_s_barrier();
  }

  const int crow0 = brow + wm * WM, ccol0 = bcol + wn * WN;
#pragma unroll
  for (int mi = 0; mi < MF; ++mi) {
    const int row0 = crow0 + mi * 16 + (lane >> 4) * 4;
    const float d0 = dis[row0], d1 = dis[row0 + 1], d2 = dis[row0 + 2],
                d3 = dis[row0 + 3];
#pragma unroll
    for (int ni = 0; ni < NF; ++ni) {
      const int col = ccol0 + ni * 16 + l15;
      f32x4 a = acc[mi][ni];
      if constexpr (EPI == 0) {
        ushort4v o = {f2b(d0 * a.x), f2b(d1 * a.y), f2b(d2 * a.z),
                      f2b(d3 * a.w)};
        *reinterpret_cast<ushort4v*>(outb + (size_t)col * M + row0) = o;
      } else if constexpr (EPI == 1) {
        const float bb = bias[col];
        float v0 = d0 * a.x + bb; v0 = v0 > 0.f ? v0 : 0.f;
        float v1 = d1 * a.y + bb; v1 = v1 > 0.f ? v1 : 0.f;
        float v2 = d2 * a.z + bb; v2 = v2 > 0.f ? v2 : 0.f;
        float v3 = d3 * a.w + bb; v3 = v3 > 0.f ? v3 : 0.f;
        outb[(size_t)(row0 + 0) * N + col] = f2b(v0);
        outb[(size_t)(row0 + 1) * N + col] = f2b(v1);
        outb[(size_t)(row0 + 2) * N + col] = f2b(v2);
        outb[(size_t)(row0 + 3) * N + col] = f2b(v3);
      } else {
        const float bb = bias[col];
        outf[(size_t)(row0 + 0) * N + col] = d0 * a.x + bb;
        outf[(size_t)(row0 + 1) * N + col] = d1 * a.y + bb;
        outf[(size_t)(row0 + 2) * N + col] = d2 * a.z + bb;
        outf[(size_t)(row0 + 3) * N + col] = d3 * a.w + bb;
      }
    }
  }
}

// ---------------------------------------------------------------------------
// Unified big split-K GEMM: 128x128 tile, 2-deep dbuf = 64 KB -> 2 blocks/CU.
// Swizzled LDS + setprio + counted vmcnt. bf16 P partials.
// ---------------------------------------------------------------------------
__global__ __launch_bounds__(512, 4) void k_gemm_big(
    const unsigned short* __restrict__ Ag,   // [8192][8192] At
    const unsigned short* __restrict__ BTg,  // [N][8192]
    int N, int Kchunk, int gx, int ncol,
    unsigned short* __restrict__ P) {        // bf16 partials
  constexpr int M = 8192, Kstride = 8192;
  constexpr int NLOADS = 4;
  __shared__ unsigned short Als[2][128][64];
  __shared__ unsigned short Bls[2][128][64];

  const int nblk = gridDim.x;
  const int flat = blockIdx.x;
  const int cpx = nblk >> 3;
  const int swz = (flat & 7) * cpx + (flat >> 3);
  const int bx = swz % gx;
  const int rem = swz / gx;
  const int by = rem % ncol;
  const int bz = rem / ncol;

  const int tid = threadIdx.x;
  const int lane = tid & 63;
  const int wid = tid >> 6;
  const int wm = wid >> 2, wn = wid & 3;
  const int brow = bx * 128;
  const int bcol = by * 128;
  const int kbase = bz * Kchunk;
  const int ar = tid >> 3;
  const int acs = ((tid & 7) ^ (ar & 7)) * 8;
  const int l15 = lane & 15;
  const int lk = (lane >> 4) * 8;
  const int rk = (l15 & 7) * 8;

  f32x4 acc[4][2];
#pragma unroll
  for (int i = 0; i < 4; ++i)
#pragma unroll
    for (int j = 0; j < 2; ++j) acc[i][j] = (f32x4){0.f, 0.f, 0.f, 0.f};

  auto stage = [&](int buf, int k0) {
#pragma unroll
    for (int i = 0; i < 2; ++i) {
      const unsigned short* g =
          Ag + (size_t)(brow + i * 64 + ar) * Kstride + k0 + acs;
      __builtin_amdgcn_global_load_lds(
          (const __attribute__((address_space(1))) void*)g,
          (__attribute__((address_space(3))) void*)
              &Als[buf][i * 64 + ar][(tid & 7) * 8],
          16, 0, 0);
    }
#pragma unroll
    for (int i = 0; i < 2; ++i) {
      const unsigned short* g =
          BTg + (size_t)(bcol + i * 64 + ar) * Kstride + k0 + acs;
      __builtin_amdgcn_global_load_lds(
          (const __attribute__((address_space(1))) void*)g,
          (__attribute__((address_space(3))) void*)
              &Bls[buf][i * 64 + ar][(tid & 7) * 8],
          16, 0, 0);
    }
  };

  const int nsteps = Kchunk / 64;
  stage(0, kbase);
  for (int t = 0; t < nsteps; ++t) {
    const int cur = t & 1;
    if (t + 1 < nsteps) {
      stage(cur ^ 1, kbase + (t + 1) * 64);
      asm volatile("s_waitcnt vmcnt(%0)" ::"n"(NLOADS));
    } else {
      asm volatile("s_waitcnt vmcnt(0)");
    }
    __builtin_amdgcn_s_barrier();
    asm volatile("" ::: "memory");
#pragma unroll
    for (int kk = 0; kk < 2; ++kk) {
      bf16x8 afr[4], bfr[2];
#pragma unroll
      for (int mi = 0; mi < 4; ++mi)
        afr[mi] = *reinterpret_cast<const bf16x8*>(
            &Als[cur][wm * 64 + mi * 16 + l15][(kk * 32 + lk) ^ rk]);
#pragma unroll
      for (int ni = 0; ni < 2; ++ni)
        bfr[ni] = *reinterpret_cast<const bf16x8*>(
            &Bls[cur][wn * 32 + ni * 16 + l15][(kk * 32 + lk) ^ rk]);
      __builtin_amdgcn_s_setprio(1);
#pragma unroll
      for (int mi = 0; mi < 4; ++mi)
#pragma unroll
        for (int ni = 0; ni < 2; ++ni)
          acc[mi][ni] = __builtin_amdgcn_mfma_f32_16x16x32_bf16(
              afr[mi], bfr[ni], acc[mi][ni], 0, 0, 0);
      __builtin_amdgcn_s_setprio(0);
    }
    asm volatile("" ::: "memory");
    __builtin_amdgcn_s_barrier();
  }

  unsigned short* Pz = P + (size_t)bz * M * N;
  const int crow0 = brow + wm * 64, ccol0 = bcol + wn * 32;
#pragma unroll
  for (int mi = 0; mi < 4; ++mi) {
    const int row0 = crow0 + mi * 16 + (lane >> 4) * 4;
#pragma unroll
    for (int ni = 0; ni < 2; ++ni) {
      const int col = ccol0 + ni * 16 + l15;
      f32x4 a = acc[mi][ni];
      Pz[(size_t)(row0 + 0) * N + col] = f2b(a.x);
      Pz[(size_t)(row0 + 1) * N + col] = f2b(a.y);
      Pz[(size_t)(row0 + 2) * N + col] = f2b(a.z);
      Pz[(size_t)(row0 + 3) * N + col] = f2b(a.w);
    }
  }
}

// ---------------------------------------------------------------------------
// Fused reduce (4 bf16 slabs) + GEMM5: h = relu(dis*ΣP+b1) -> swizzled LDS;
// M2T = (dis ⊙ (h @ W2))^T.
// ---------------------------------------------------------------------------
__global__ __launch_bounds__(256, 2) void k_h_gemm(
    const unsigned short* __restrict__ P,    // [4][8192][256] bf16
    const unsigned short* __restrict__ W2T,  // [128][256]
    const float* __restrict__ dis, const float* __restrict__ b1,
    unsigned short* __restrict__ M2T) {      // [128][8192]
  __shared__ unsigned short W2ls[128][256];
  __shared__ unsigned short hls[32][256];
  const int tid = threadIdx.x;
  const int lane = tid & 63;
  const int l15 = lane & 15;
  const int wid = tid >> 6;
  const int m0 = blockIdx.x * 32;

  {
    const int wr = tid >> 5, wc = tid & 31;
#pragma unroll
    for (int i = 0; i < 16; ++i) {
      const int row = i * 8 + wr;
      const unsigned short* g = W2T + row * 256 + ((wc ^ (row & 7)) * 8);
      __builtin_amdgcn_global_load_lds(
          (const __attribute__((address_space(1))) void*)g,
          (__attribute__((address_space(3))) void*)&W2ls[row][wc * 8], 16, 0,
          0);
    }
  }

  {
    const int col4 = (tid & 63) * 4;
    const int rsub = tid >> 6;  // 0..3
    const float4v bv = *reinterpret_cast<const float4v*>(b1 + col4);
    const int ch = (tid & 63) >> 1;
    const int sub = (tid & 1) * 4;
#pragma unroll
    for (int p = 0; p < 8; ++p) {
      const int row = p * 4 + rsub;
      const size_t off = (size_t)(m0 + row) * 256 + col4;
      float r0 = 0.f, r1 = 0.f, r2 = 0.f, r3 = 0.f;
#pragma unroll
      for (int z = 0; z < 4; ++z) {
        ushort4v v =
            *reinterpret_cast<const ushort4v*>(P + (size_t)z * 2097152 + off);
        r0 += b2f(v.x); r1 += b2f(v.y); r2 += b2f(v.z); r3 += b2f(v.w);
      }
      const float dm = dis[m0 + row];
      r0 = dm * r0 + bv.x;
      r1 = dm * r1 + bv.y;
      r2 = dm * r2 + bv.z;
      r3 = dm * r3 + bv.w;
      r0 = r0 > 0.f ? r0 : 0.f;
      r1 = r1 > 0.f ? r1 : 0.f;
      r2 = r2 > 0.f ? r2 : 0.f;
      r3 = r3 > 0.f ? r3 : 0.f;
      ushort4v o = {f2b(r0), f2b(r1), f2b(r2), f2b(r3)};
      *reinterpret_cast<ushort4v*>(
          &hls[row][(ch ^ (row & 7)) * 8 + sub]) = o;
    }
  }
  __syncthreads();

  f32x4 acc[2][2];
#pragma unroll
  for (int i = 0; i < 2; ++i)
#pragma unroll
    for (int j = 0; j < 2; ++j) acc[i][j] = (f32x4){0.f, 0.f, 0.f, 0.f};

#pragma unroll
  for (int kk = 0; kk < 8; ++kk) {
    const int gch = kk * 4 + (lane >> 4);
    bf16x8 a[2], b[2];
#pragma unroll
    for (int mi = 0; mi < 2; ++mi) {
      const int mr = mi * 16 + l15;
      a[mi] =
          *reinterpret_cast<const bf16x8*>(&hls[mr][(gch ^ (mr & 7)) * 8]);
    }
#pragma unroll
    for (int ni = 0; ni < 2; ++ni) {
      const int nr = wid * 32 + ni * 16 + l15;
      b[ni] =
          *reinterpret_cast<const bf16x8*>(&W2ls[nr][(gch ^ (nr & 7)) * 8]);
    }
#pragma unroll
    for (int mi = 0; mi < 2; ++mi)
#pragma unroll
      for (int ni = 0; ni < 2; ++ni)
        acc[mi][ni] = __builtin_amdgcn_mfma_f32_16x16x32_bf16(
            a[mi], b[ni], acc[mi][ni], 0, 0, 0);
  }

#pragma unroll
  for (int mi = 0; mi < 2; ++mi) {
    const int r0 = mi * 16 + (lane >> 4) * 4;
    const float d0 = dis[m0 + r0], d1 = dis[m0 + r0 + 1],
                d2 = dis[m0 + r0 + 2], d3 = dis[m0 + r0 + 3];
#pragma unroll
    for (int ni = 0; ni < 2; ++ni) {
      const int col = wid * 32 + ni * 16 + l15;
      f32x4 a = acc[mi][ni];
      ushort4v o = {f2b(d0 * a.x), f2b(d1 * a.y), f2b(d2 * a.z),
                    f2b(d3 * a.w)};
      *reinterpret_cast<ushort4v*>(&M2T[(size_t)col * 8192 + m0 + r0]) = o;
    }
  }
}

// ---------------------------------------------------------------------------
// Split-K reduction over bf16 partials: outf = dis*Σ + b  (f32 final out)
// ---------------------------------------------------------------------------
template <int NS>
__global__ __launch_bounds__(256) void k_reduceN(
    const unsigned short* __restrict__ P, int M, int N,
    const float* __restrict__ dis, const float* __restrict__ bias,
    float* __restrict__ outf) {
  const int idx = blockIdx.x * 256 + threadIdx.x;
  const int row = idx / (N / 4);
  const int c0 = (idx - row * (N / 4)) * 4;
  const size_t off = (size_t)row * N + c0;
  const size_t ps = (size_t)M * N;
  float r0 = 0.f, r1 = 0.f, r2 = 0.f, r3 = 0.f;
#pragma unroll
  for (int z = 0; z < NS; ++z) {
    ushort4v v = *reinterpret_cast<const ushort4v*>(P + z * ps + off);
    r0 += b2f(v.x); r1 += b2f(v.y); r2 += b2f(v.z); r3 += b2f(v.w);
  }
  const float d = dis[row];
  float4v bb = *reinterpret_cast<const float4v*>(bias + c0);
  float4v o = {d * r0 + bb.x, d * r1 + bb.y, d * r2 + bb.z, d * r3 + bb.w};
  *reinterpret_cast<float4v*>(outf + off) = o;
}

// ---------------------------------------------------------------------------
extern "C" void kernel_launch(void* const* d_in, const int* in_sizes, int n_in,
                              void* d_out, int out_size, void* d_ws,
                              size_t ws_size, hipStream_t stream) {
  const float* A  = (const float*)d_in[0];
  const float* S  = (const float*)d_in[1];
  const float* x  = (const float*)d_in[2];
  const float* W1 = (const float*)d_in[3];
  const float* b1 = (const float*)d_in[4];
  const float* W2 = (const float*)d_in[5];
  const float* b2 = (const float*)d_in[6];
  float* out = (float*)d_out;

  char* ws = (char*)d_ws;
  dim3 blk(256);

  // P is bf16: max(L1 4x8192x256, L2 8x8192x128) x 2B = 16 MB.
  const size_t O_At = 0, O_xb = 134217728, O_M1T = 142606336,
               O_P = 146800640, O_W1T = 180355072, O_W2T = 180617216,
               O_dis = 180682752, NEED = 180715520;

  if (ws_size >= NEED) {
    unsigned short* At  = (unsigned short*)(ws + O_At);
    unsigned short* xb  = (unsigned short*)(ws + O_xb);
    unsigned short* M1T = (unsigned short*)(ws + O_M1T);
    unsigned short* P   = (unsigned short*)(ws + O_P);
    unsigned short* M2T = (unsigned short*)(ws + O_xb);   // overlay xb
    unsigned short* W1T = (unsigned short*)(ws + O_W1T);
    unsigned short* W2T = (unsigned short*)(ws + O_W2T);
    float*          dis = (float*)(ws + O_dis);

    // 1. degree + all conversions (merged)
    k_degree_conv<<<12928, blk, 0, stream>>>(A, S, At, dis, x, xb, W1, W1T,
                                             W2, W2T);
    // 2. M1^T = (dis ⊙ (x @ W1))^T   [256][8192]
    k_gemm_bt<128, 64, 0><<<dim3(64, 4), blk, 0, stream>>>(
        xb, W1T, 8192, 256, 512, 512, dis, nullptr, nullptr, M1T);
    // 3. P[z] = (At @ M1)_z   SK=4, ncol=2, 128x128 tiles, 2 blocks/CU
    k_gemm_big<<<dim3(512), dim3(512), 0, stream>>>(At, M1T, 256, 2048, 64, 2,
                                                    P);
    // 4. fused: h = relu(dis*ΣP+b1); M2T = (dis ⊙ (h @ W2))^T
    k_h_gemm<<<256, blk, 0, stream>>>(P, W2T, dis, b1, M2T);
    // 5. P[z] = (At @ M2)_z   SK=8, ncol=1, 128x128 tiles, 2 blocks/CU
    k_gemm_big<<<dim3(512), dim3(512), 0, stream>>>(At, M2T, 128, 1024, 64, 1,
                                                    P);
    // 6. out = dis*ΣP + b2  f32
    k_reduceN<8><<<1024, blk, 0, stream>>>(P, 8192, 128, dis, b2, out);
  } else {
    unsigned short* At  = (unsigned short*)(ws);
    unsigned short* xb  = (unsigned short*)(ws + 134217728);
    unsigned short* M1T = (unsigned short*)(ws + 142606336);
    unsigned short* hb  = (unsigned short*)(ws + 146800640);
    unsigned short* M2T = (unsigned short*)(ws + 150994944);
    unsigned short* W1T = (unsigned short*)(ws + 153092096);
    unsigned short* W2T = (unsigned short*)(ws + 153354240);
    float* dis          = (float*)(ws + 153419776);

    k_degree_convert<<<8192, blk, 0, stream>>>(A, S, At, dis);
    k_conv_all<<<4736, blk, 0, stream>>>(x, xb, W1, W1T, W2, W2T);
    k_gemm_bt<128, 64, 0><<<dim3(64, 4), blk, 0, stream>>>(
        xb, W1T, 8192, 256, 512, 512, dis, nullptr, nullptr, M1T);
    k_gemm_bt<128, 64, 1><<<dim3(64, 4), blk, 0, stream>>>(
        At, M1T, 8192, 256, 8192, 8192, dis, b1, nullptr, hb);
    k_gemm_bt<64, 64, 0><<<dim3(128, 2), blk, 0, stream>>>(
        hb, W2T, 8192, 128, 256, 256, dis, nullptr, nullptr, M2T);
    k_gemm_bt<64, 64, 2><<<dim3(128, 2), blk, 0, stream>>>(
        At, M2T, 8192, 128, 8192, 8192, dis, b2, out, nullptr);
  }
}